// Round 20
// baseline (101.327 us; speedup 1.0000x reference)
//
#include <hip/hip_runtime.h>

#define Cc 8
#define Hh 128
#define Ww 128
#define Nn 64
#define Bb 8
#define Dd 169            // (C+2)*C + C + C*C + C + C + 1
#define HW (Hh * Ww)
#define NP 2              // n-pairs per block (4 n's)
#define NPG 16            // n-pair groups per batch (32/NP)
#define PXS 1024          // pixels per stripe (block)
#define NSTRIPE (HW / PXS)          // 16
#define NBLK (Bb * NPG * NSTRIPE)   // 2048 blocks
#define FRAGW 16                    // u32 per lane per n-pair in frag table
#define FRAG_U32 (256 * 64 * FRAGW) // 256 n-pairs total

#define INV128 (1.0f / 128.0f)

typedef __fp16 f16x2 __attribute__((ext_vector_type(2)));
typedef _Float16 h8 __attribute__((ext_vector_type(8)));
typedef float f32x4 __attribute__((ext_vector_type(4)));

static __device__ __forceinline__ uint32_t pku(float a, float b) {
    f16x2 t = __builtin_amdgcn_cvt_pkrtz(a, b);
    uint32_t u; __builtin_memcpy(&u, &t, 4); return u;
}
static __device__ __forceinline__ h8 u4h8(uint32_t a, uint32_t b, uint32_t c, uint32_t d) {
    uint32_t u[4] = {a, b, c, d}; h8 r; __builtin_memcpy(&r, u, 16); return r;
}

// ---- kernel A: per-lane MFMA fragments per n-pair (r16..r19 layout, validated) ----
// L1 k = 8g+e (k10 = const-1 carrying bias + x0/y0 fold). L2 k2 = 4g+e, plus
// bias slot: B2 elem4 on g==0 = 1.0, A2 elem4 (g==0) = b2[row].
// Slots/lane: [0..3]=A1, [4..6]=A2(+bias), [7..10]=w3 f32, [11]=b3, [12]=m^2
__global__ void pack_frags(const float* __restrict__ conv_weight,
                           const float* __restrict__ mask,
                           const int*   __restrict__ ind,
                           uint32_t*    __restrict__ frag) {
    const int npair = blockIdx.x * 4 + (threadIdx.x >> 6);   // 64 blocks x 4 waves
    const int b     = npair >> 5;
    const int bn0   = b * Nn + 2 * (npair & 31);
    const int l  = threadIdx.x & 63;
    const int g  = l >> 4, r = l & 15, rr = r & 7;
    const int bnr = bn0 + (r >> 3);          // row-owner n
    const int bng = bn0 + (g >> 1);          // D-row-group owner n
    const float* base = conv_weight + (size_t)b * Dd * HW;
    const float* srcR = base + ind[bnr];
    const float* srcG = base + ind[bng];

    float a1[8];
    #pragma unroll
    for (int e = 0; e < 8; ++e) {
        const int k = 8 * g + e;
        float v = 0.f;
        if (k < 8)       v = srcR[(size_t)(rr * 10 + k) * HW];
        else if (k == 8) v = srcR[(size_t)(rr * 10 + 8) * HW];
        else if (k == 9) v = srcR[(size_t)(rr * 10 + 9) * HW];
        else if (k == 10) {
            const float w8 = srcR[(size_t)(rr * 10 + 8) * HW];
            const float w9 = srcR[(size_t)(rr * 10 + 9) * HW];
            const float b1 = srcR[(size_t)(80 + rr) * HW];
            const int   ib = ind[bnr];
            v = b1 - w8 * ((float)(ib & 127) * INV128)
                   - w9 * ((float)(ib >> 7) * INV128);
        }
        a1[e] = v;
    }
    float a2[4];
    #pragma unroll
    for (int e = 0; e < 4; ++e) {
        const int k2 = 4 * g + e;
        float v = 0.f;
        if (r < 8)  { if (k2 < 8)  v = srcR[(size_t)(88 + rr * 8 + k2) * HW]; }
        else        { if (k2 >= 8) v = srcR[(size_t)(88 + rr * 8 + (k2 - 8)) * HW]; }
        a2[e] = v;
    }
    const float b2bias = (g == 0) ? srcR[(size_t)(152 + rr) * HW] : 0.f;

    float w3v[4];
    #pragma unroll
    for (int j = 0; j < 4; ++j) {
        const int c = (4 * g + j) & 7;
        w3v[j] = srcG[(size_t)(160 + c) * HW];
    }
    const float b3 = srcG[(size_t)168 * HW];
    const float mm = mask[bng];

    uint32_t* dst = frag + ((size_t)npair * 64 + l) * FRAGW;
    dst[0] = pku(a1[0], a1[1]); dst[1] = pku(a1[2], a1[3]);
    dst[2] = pku(a1[4], a1[5]); dst[3] = pku(a1[6], a1[7]);
    dst[4] = pku(a2[0], a2[1]); dst[5] = pku(a2[2], a2[3]);
    dst[6] = pku(b2bias, 0.f);
    float* df = (float*)dst;
    df[7] = w3v[0]; df[8] = w3v[1]; df[9] = w3v[2]; df[10] = w3v[3];
    df[11] = b3; df[12] = mm * mm;
    dst[13] = 0u; dst[14] = 0u; dst[15] = 0u;
}

// ---- kernel B: r19 main + fused final reduction (atomics + last-block loss) ----
__global__ __launch_bounds__(256)
__attribute__((amdgpu_waves_per_eu(4, 8)))
void seg_dice_main(const float* __restrict__ seg_feat,
                   const float* __restrict__ target,
                   const uint32_t* __restrict__ frag,
                   float* __restrict__ acc,      // 24 floats, zeroed per call
                   unsigned* __restrict__ cnt,   // 1 counter, zeroed per call
                   float* __restrict__ out) {
    const int bid    = blockIdx.x;
    const int b      = bid & 7;
    const int rest   = bid >> 3;           // 0..255
    const int npg    = rest & 15;
    const int stripe = rest >> 4;          // 0..15
    const int p0     = stripe * PXS;
    const int tid  = threadIdx.x;
    const int wave = tid >> 6;
    const int l    = tid & 63;
    const int g    = l >> 4, col = l & 15;

    __shared__ uint4 lds4[PXS];            // pixel-major seg tile: 8 f16/px

    const float* seg_b = seg_feat + (size_t)b * Cc * HW;
    #pragma unroll
    for (int q = 0; q < 4; ++q) {
        const int px = q * 256 + tid;
        float v[8];
        #pragma unroll
        for (int c = 0; c < 8; ++c) v[c] = seg_b[(size_t)c * HW + p0 + px];
        lds4[px] = uint4{pku(v[0], v[1]), pku(v[2], v[3]),
                         pku(v[4], v[5]), pku(v[6], v[7])};
    }

    // per-lane fragments for the 2 n-pairs; A-operands built ONCE as h8
    const int npair0 = b * 32 + npg * NP;
    const int par = g & 1;
    h8 A1h[NP], A2h[NP];
    float w3v[NP][4];
    float flS = 0.f, b3S = 0.f;
    const float* ptrS = target;
    #pragma unroll
    for (int j = 0; j < NP; ++j) {
        const uint4* fp = (const uint4*)(frag + ((size_t)(npair0 + j) * 64 + l) * FRAGW);
        const uint4 q0 = fp[0], q1 = fp[1], q2 = fp[2];
        const uint32_t q3x = ((const uint32_t*)fp)[12];
        A1h[j] = u4h8(q0.x, q0.y, q0.z, q0.w);
        A2h[j] = u4h8(q1.x, q1.y, q1.z, 0u);
        w3v[j][0] = __uint_as_float(q1.w);
        w3v[j][1] = __uint_as_float(q2.x);
        w3v[j][2] = __uint_as_float(q2.y);
        w3v[j][3] = __uint_as_float(q2.z);
        if (j == par) {
            b3S = __uint_as_float(q2.w);
            flS = __uint_as_float(q3x);
            const int bnS = b * Nn + 2 * (npg * NP + j) + (l >> 5);
            ptrS = target + (size_t)bnS * HW + p0 + col;
        }
    }
    __syncthreads();

    const uint32_t one16 = 0x3C00u;
    const uint32_t b2one = (g == 0) ? one16 : 0u;
    const f32x4 ZF = {0.f, 0.f, 0.f, 0.f};
    float inter = 0.f, ps = 0.f, ts = 0.f;

    #pragma unroll 1
    for (int tt = wave; tt < 64; tt += 8) {
        const int pu = tt * 16;            // tile u
        const int pv = pu + 64;            // tile v = tt+4
        const int pxgu = p0 + pu + col;
        const int pxgv = p0 + pv + col;

        const float tvu = ptrS[pu];
        const float tvv = ptrS[pv];
        const uint4 du = lds4[pu + col];
        const uint4 dv = lds4[pv + col];

        const uint32_t xvu = pku((float)(pxgu & 127) * INV128,
                                 (float)(pxgu >> 7) * INV128);
        const uint32_t xvv = pku((float)(pxgv & 127) * INV128,
                                 (float)(pxgv >> 7) * INV128);
        const h8 B1u = u4h8((g == 0) ? du.x : ((g == 1) ? xvu : 0u),
                            (g == 0) ? du.y : ((g == 1) ? one16 : 0u),
                            (g == 0) ? du.z : 0u,
                            (g == 0) ? du.w : 0u);
        const h8 B1v = u4h8((g == 0) ? dv.x : ((g == 1) ? xvv : 0u),
                            (g == 0) ? dv.y : ((g == 1) ? one16 : 0u),
                            (g == 0) ? dv.z : 0u,
                            (g == 0) ? dv.w : 0u);

        f32x4 h1au = __builtin_amdgcn_mfma_f32_16x16x32_f16(A1h[0], B1u, ZF, 0, 0, 0);
        f32x4 h1bu = __builtin_amdgcn_mfma_f32_16x16x32_f16(A1h[1], B1u, ZF, 0, 0, 0);
        f32x4 h1av = __builtin_amdgcn_mfma_f32_16x16x32_f16(A1h[0], B1v, ZF, 0, 0, 0);
        f32x4 h1bv = __builtin_amdgcn_mfma_f32_16x16x32_f16(A1h[1], B1v, ZF, 0, 0, 0);
        #pragma unroll
        for (int e = 0; e < 4; ++e) {
            h1au[e] = fmaxf(h1au[e], 0.f); h1bu[e] = fmaxf(h1bu[e], 0.f);
            h1av[e] = fmaxf(h1av[e], 0.f); h1bv[e] = fmaxf(h1bv[e], 0.f);
        }
        const h8 B2au = u4h8(pku(h1au[0], h1au[1]), pku(h1au[2], h1au[3]), b2one, 0u);
        const h8 B2bu = u4h8(pku(h1bu[0], h1bu[1]), pku(h1bu[2], h1bu[3]), b2one, 0u);
        const h8 B2av = u4h8(pku(h1av[0], h1av[1]), pku(h1av[2], h1av[3]), b2one, 0u);
        const h8 B2bv = u4h8(pku(h1bv[0], h1bv[1]), pku(h1bv[2], h1bv[3]), b2one, 0u);

        f32x4 h2au = __builtin_amdgcn_mfma_f32_16x16x32_f16(A2h[0], B2au, ZF, 0, 0, 0);
        f32x4 h2bu = __builtin_amdgcn_mfma_f32_16x16x32_f16(A2h[1], B2bu, ZF, 0, 0, 0);
        f32x4 h2av = __builtin_amdgcn_mfma_f32_16x16x32_f16(A2h[0], B2av, ZF, 0, 0, 0);
        f32x4 h2bv = __builtin_amdgcn_mfma_f32_16x16x32_f16(A2h[1], B2bv, ZF, 0, 0, 0);

        float zpau = fmaxf(h2au[0], 0.f) * w3v[0][0];
        float zpav = fmaxf(h2av[0], 0.f) * w3v[0][0];
        zpau = fmaf(fmaxf(h2au[1], 0.f), w3v[0][1], zpau);
        zpav = fmaf(fmaxf(h2av[1], 0.f), w3v[0][1], zpav);
        zpau = fmaf(fmaxf(h2au[2], 0.f), w3v[0][2], zpau);
        zpav = fmaf(fmaxf(h2av[2], 0.f), w3v[0][2], zpav);
        zpau = fmaf(fmaxf(h2au[3], 0.f), w3v[0][3], zpau);
        zpav = fmaf(fmaxf(h2av[3], 0.f), w3v[0][3], zpav);
        float zpbu = fmaxf(h2bu[0], 0.f) * w3v[1][0];
        float zpbv = fmaxf(h2bv[0], 0.f) * w3v[1][0];
        zpbu = fmaf(fmaxf(h2bu[1], 0.f), w3v[1][1], zpbu);
        zpbv = fmaf(fmaxf(h2bv[1], 0.f), w3v[1][1], zpbv);
        zpbu = fmaf(fmaxf(h2bu[2], 0.f), w3v[1][2], zpbu);
        zpbv = fmaf(fmaxf(h2bv[2], 0.f), w3v[1][2], zpbv);
        zpbu = fmaf(fmaxf(h2bu[3], 0.f), w3v[1][3], zpbu);
        zpbv = fmaf(fmaxf(h2bv[3], 0.f), w3v[1][3], zpbv);

        zpau += __shfl_xor(zpau, 16);
        zpav += __shfl_xor(zpav, 16);
        zpbu += __shfl_xor(zpbu, 16);
        zpbv += __shfl_xor(zpbv, 16);

        const float zu = (par ? zpbu : zpau) + b3S;
        const float zv = (par ? zpbv : zpav) + b3S;
        const float ou = __builtin_amdgcn_rcpf(1.f + __expf(-zu));
        const float ov = __builtin_amdgcn_rcpf(1.f + __expf(-zv));
        const float fou = flS * ou;
        const float fov = flS * ov;
        inter = fmaf(fou, tvu, inter);
        inter = fmaf(fov, tvv, inter);
        ps    = fmaf(fou, ou, ps);
        ps    = fmaf(fov, ov, ps);
        ts    = fmaf(flS, tvu * tvu, ts);
        ts    = fmaf(flS, tvv * tvv, ts);
    }

    // wave reduce then cross-wave
    #pragma unroll
    for (int off = 32; off > 0; off >>= 1) {
        inter += __shfl_down(inter, off);
        ps    += __shfl_down(ps,    off);
        ts    += __shfl_down(ts,    off);
    }
    __shared__ float red[3][4];
    if ((tid & 63) == 0) { red[0][wave] = inter; red[1][wave] = ps; red[2][wave] = ts; }
    __syncthreads();
    if (tid == 0) {
        const float i2 = red[0][0] + red[0][1] + red[0][2] + red[0][3];
        const float p2 = red[1][0] + red[1][1] + red[1][2] + red[1][3];
        const float t2 = red[2][0] + red[2][1] + red[2][2] + red[2][3];
        atomicAdd(&acc[b * 3 + 0], i2);
        atomicAdd(&acc[b * 3 + 1], p2);
        atomicAdd(&acc[b * 3 + 2], t2);
        __threadfence();
        const unsigned done = atomicAdd(cnt, 1u);
        if (done == (unsigned)(NBLK - 1)) {
            __threadfence();
            float loss = 0.f;
            #pragma unroll
            for (int bb = 0; bb < Bb; ++bb) {
                const float I = atomicAdd(&acc[bb * 3 + 0], 0.f);
                const float P = atomicAdd(&acc[bb * 3 + 1], 0.f);
                const float T = atomicAdd(&acc[bb * 3 + 2], 0.f);
                loss += 1.f - (2.f * I + 1.f) / (P + T + 1.f);
            }
            out[0] = loss * (1.f / (float)Bb);
        }
    }
}

extern "C" void kernel_launch(void* const* d_in, const int* in_sizes, int n_in,
                              void* d_out, int out_size, void* d_ws, size_t ws_size,
                              hipStream_t stream) {
    const float* seg_feat    = (const float*)d_in[0];
    const float* conv_weight = (const float*)d_in[1];
    const float* mask        = (const float*)d_in[2];
    const int*   ind         = (const int*)d_in[3];
    const float* target      = (const float*)d_in[4];
    float* out = (float*)d_out;

    uint32_t* fragtab = (uint32_t*)d_ws;
    float*    acc     = (float*)d_ws + FRAG_U32;        // 24 floats
    unsigned* cnt     = (unsigned*)(acc + 24);          // 1 counter

    hipMemsetAsync(acc, 0, 25 * sizeof(float), stream); // zero acc + cnt

    pack_frags<<<64, 256, 0, stream>>>(conv_weight, mask, ind, fragtab);
    seg_dice_main<<<NBLK, 256, 0, stream>>>(seg_feat, target, fragtab, acc, cnt, out);
}

// Round 21
// 35.862 us; speedup vs baseline: 2.8255x; 2.8255x over previous
//
#include <hip/hip_runtime.h>

#define Cc 8
#define Hh 128
#define Ww 128
#define Nn 64
#define Bb 8
#define Dd 169            // (C+2)*C + C + C*C + C + C + 1
#define HW (Hh * Ww)
#define NP 2              // n-pairs per block (4 n's)
#define NPG 16            // n-pair groups per batch (32/NP)
#define PXS 1024          // pixels per stripe (block)
#define NSTRIPE (HW / PXS)          // 16
#define NBLK (Bb * NPG * NSTRIPE)   // 2048 blocks
#define FRAGW 16                    // u32 per lane per n-pair in frag table
#define FRAG_U32 (256 * 64 * FRAGW) // 256 n-pairs total
#define SLOTS (NPG * NSTRIPE)       // 256 reduction slots per batch

#define INV128 (1.0f / 128.0f)

typedef __fp16 f16x2 __attribute__((ext_vector_type(2)));
typedef _Float16 h8 __attribute__((ext_vector_type(8)));
typedef float f32x4 __attribute__((ext_vector_type(4)));

static __device__ __forceinline__ uint32_t pku(float a, float b) {
    f16x2 t = __builtin_amdgcn_cvt_pkrtz(a, b);
    uint32_t u; __builtin_memcpy(&u, &t, 4); return u;
}
static __device__ __forceinline__ h8 u4h8(uint32_t a, uint32_t b, uint32_t c, uint32_t d) {
    uint32_t u[4] = {a, b, c, d}; h8 r; __builtin_memcpy(&r, u, 16); return r;
}

// ---- kernel A: per-lane MFMA fragments per n-pair (r16/r17 layout, validated) ----
// L1 k = 8g+e (k10 = const-1 carrying bias + x0/y0 fold). L2 k2 = 4g+e, plus
// bias slot: B2 elem4 on g==0 = 1.0, A2 elem4 (g==0) = b2[row].
// Slots/lane: [0..3]=A1, [4..6]=A2(+bias), [7..10]=w3 f32, [11]=b3, [12]=m^2
__global__ void pack_frags(const float* __restrict__ conv_weight,
                           const float* __restrict__ mask,
                           const int*   __restrict__ ind,
                           uint32_t*    __restrict__ frag) {
    const int npair = blockIdx.x;            // 0..255
    const int b     = npair >> 5;
    const int bn0   = b * Nn + 2 * (npair & 31);
    const int l  = threadIdx.x;              // 0..63
    const int g  = l >> 4, r = l & 15, rr = r & 7;
    const int bnr = bn0 + (r >> 3);          // row-owner n
    const int bng = bn0 + (g >> 1);          // D-row-group owner n
    const float* base = conv_weight + (size_t)b * Dd * HW;
    const float* srcR = base + ind[bnr];
    const float* srcG = base + ind[bng];

    float a1[8];
    #pragma unroll
    for (int e = 0; e < 8; ++e) {
        const int k = 8 * g + e;
        float v = 0.f;
        if (k < 8)       v = srcR[(size_t)(rr * 10 + k) * HW];
        else if (k == 8) v = srcR[(size_t)(rr * 10 + 8) * HW];
        else if (k == 9) v = srcR[(size_t)(rr * 10 + 9) * HW];
        else if (k == 10) {
            const float w8 = srcR[(size_t)(rr * 10 + 8) * HW];
            const float w9 = srcR[(size_t)(rr * 10 + 9) * HW];
            const float b1 = srcR[(size_t)(80 + rr) * HW];
            const int   ib = ind[bnr];
            v = b1 - w8 * ((float)(ib & 127) * INV128)
                   - w9 * ((float)(ib >> 7) * INV128);
        }
        a1[e] = v;
    }
    float a2[4];
    #pragma unroll
    for (int e = 0; e < 4; ++e) {
        const int k2 = 4 * g + e;
        float v = 0.f;
        if (r < 8)  { if (k2 < 8)  v = srcR[(size_t)(88 + rr * 8 + k2) * HW]; }
        else        { if (k2 >= 8) v = srcR[(size_t)(88 + rr * 8 + (k2 - 8)) * HW]; }
        a2[e] = v;
    }
    const float b2bias = (g == 0) ? srcR[(size_t)(152 + rr) * HW] : 0.f;

    float w3v[4];
    #pragma unroll
    for (int j = 0; j < 4; ++j) {
        const int c = (4 * g + j) & 7;
        w3v[j] = srcG[(size_t)(160 + c) * HW];
    }
    const float b3 = srcG[(size_t)168 * HW];
    const float mm = mask[bng];

    uint32_t* dst = frag + ((size_t)npair * 64 + l) * FRAGW;
    dst[0] = pku(a1[0], a1[1]); dst[1] = pku(a1[2], a1[3]);
    dst[2] = pku(a1[4], a1[5]); dst[3] = pku(a1[6], a1[7]);
    dst[4] = pku(a2[0], a2[1]); dst[5] = pku(a2[2], a2[3]);
    dst[6] = pku(b2bias, 0.f);
    float* df = (float*)dst;
    df[7] = w3v[0]; df[8] = w3v[1]; df[9] = w3v[2]; df[10] = w3v[3];
    df[11] = b3; df[12] = mm * mm;
    dst[13] = 0u; dst[14] = 0u; dst[15] = 0u;
}

// ---- kernel B: r17 + 2-way software pipeline (tiles tt, tt+4 interleaved) ----
__global__ __launch_bounds__(256)
__attribute__((amdgpu_waves_per_eu(4, 8)))
void seg_dice_main(const float* __restrict__ seg_feat,
                   const float* __restrict__ target,
                   const uint32_t* __restrict__ frag,
                   float* __restrict__ red_base) {
    const int bid    = blockIdx.x;
    const int b      = bid & 7;
    const int rest   = bid >> 3;           // 0..255
    const int npg    = rest & 15;
    const int stripe = rest >> 4;          // 0..15
    const int p0     = stripe * PXS;
    const int tid  = threadIdx.x;
    const int wave = tid >> 6;
    const int l    = tid & 63;
    const int g    = l >> 4, col = l & 15;

    __shared__ uint4 lds4[PXS];            // pixel-major seg tile: 8 f16/px

    const float* seg_b = seg_feat + (size_t)b * Cc * HW;
    #pragma unroll
    for (int q = 0; q < 4; ++q) {
        const int px = q * 256 + tid;
        float v[8];
        #pragma unroll
        for (int c = 0; c < 8; ++c) v[c] = seg_b[(size_t)c * HW + p0 + px];
        lds4[px] = uint4{pku(v[0], v[1]), pku(v[2], v[3]),
                         pku(v[4], v[5]), pku(v[6], v[7])};
    }

    // per-lane fragments for the 2 n-pairs; A-operands built ONCE as h8
    const int npair0 = b * 32 + npg * NP;
    const int par = g & 1;
    h8 A1h[NP], A2h[NP];
    float w3v[NP][4];
    float flS = 0.f, b3S = 0.f;
    const float* ptrS = target;
    #pragma unroll
    for (int j = 0; j < NP; ++j) {
        const uint4* fp = (const uint4*)(frag + ((size_t)(npair0 + j) * 64 + l) * FRAGW);
        const uint4 q0 = fp[0], q1 = fp[1], q2 = fp[2];
        const uint32_t q3x = ((const uint32_t*)fp)[12];
        A1h[j] = u4h8(q0.x, q0.y, q0.z, q0.w);
        A2h[j] = u4h8(q1.x, q1.y, q1.z, 0u);
        w3v[j][0] = __uint_as_float(q1.w);
        w3v[j][1] = __uint_as_float(q2.x);
        w3v[j][2] = __uint_as_float(q2.y);
        w3v[j][3] = __uint_as_float(q2.z);
        if (j == par) {
            b3S = __uint_as_float(q2.w);
            flS = __uint_as_float(q3x);
            const int bnS = b * Nn + 2 * (npg * NP + j) + (l >> 5);
            ptrS = target + (size_t)bnS * HW + p0 + col;
        }
    }
    __syncthreads();

    const uint32_t one16 = 0x3C00u;
    const uint32_t b2one = (g == 0) ? one16 : 0u;
    const f32x4 ZF = {0.f, 0.f, 0.f, 0.f};
    float inter = 0.f, ps = 0.f, ts = 0.f;

    #pragma unroll 1
    for (int tt = wave; tt < 64; tt += 8) {
        const int pu = tt * 16;            // tile u
        const int pv = pu + 64;            // tile v = tt+4
        const int pxgu = p0 + pu + col;
        const int pxgv = p0 + pv + col;

        // ---- issue ALL memory for both tiles up front ----
        const float tvu = ptrS[pu];
        const float tvv = ptrS[pv];
        const uint4 du = lds4[pu + col];
        const uint4 dv = lds4[pv + col];

        // ---- B1 build (u, v) ----
        const uint32_t xvu = pku((float)(pxgu & 127) * INV128,
                                 (float)(pxgu >> 7) * INV128);
        const uint32_t xvv = pku((float)(pxgv & 127) * INV128,
                                 (float)(pxgv >> 7) * INV128);
        const h8 B1u = u4h8((g == 0) ? du.x : ((g == 1) ? xvu : 0u),
                            (g == 0) ? du.y : ((g == 1) ? one16 : 0u),
                            (g == 0) ? du.z : 0u,
                            (g == 0) ? du.w : 0u);
        const h8 B1v = u4h8((g == 0) ? dv.x : ((g == 1) ? xvv : 0u),
                            (g == 0) ? dv.y : ((g == 1) ? one16 : 0u),
                            (g == 0) ? dv.z : 0u,
                            (g == 0) ? dv.w : 0u);

        // ---- L1 MFMAs: 4 independent ----
        f32x4 h1au = __builtin_amdgcn_mfma_f32_16x16x32_f16(A1h[0], B1u, ZF, 0, 0, 0);
        f32x4 h1bu = __builtin_amdgcn_mfma_f32_16x16x32_f16(A1h[1], B1u, ZF, 0, 0, 0);
        f32x4 h1av = __builtin_amdgcn_mfma_f32_16x16x32_f16(A1h[0], B1v, ZF, 0, 0, 0);
        f32x4 h1bv = __builtin_amdgcn_mfma_f32_16x16x32_f16(A1h[1], B1v, ZF, 0, 0, 0);
        #pragma unroll
        for (int e = 0; e < 4; ++e) {
            h1au[e] = fmaxf(h1au[e], 0.f); h1bu[e] = fmaxf(h1bu[e], 0.f);
            h1av[e] = fmaxf(h1av[e], 0.f); h1bv[e] = fmaxf(h1bv[e], 0.f);
        }
        const h8 B2au = u4h8(pku(h1au[0], h1au[1]), pku(h1au[2], h1au[3]), b2one, 0u);
        const h8 B2bu = u4h8(pku(h1bu[0], h1bu[1]), pku(h1bu[2], h1bu[3]), b2one, 0u);
        const h8 B2av = u4h8(pku(h1av[0], h1av[1]), pku(h1av[2], h1av[3]), b2one, 0u);
        const h8 B2bv = u4h8(pku(h1bv[0], h1bv[1]), pku(h1bv[2], h1bv[3]), b2one, 0u);

        // ---- L2 MFMAs: 4 independent ----
        f32x4 h2au = __builtin_amdgcn_mfma_f32_16x16x32_f16(A2h[0], B2au, ZF, 0, 0, 0);
        f32x4 h2bu = __builtin_amdgcn_mfma_f32_16x16x32_f16(A2h[1], B2bu, ZF, 0, 0, 0);
        f32x4 h2av = __builtin_amdgcn_mfma_f32_16x16x32_f16(A2h[0], B2av, ZF, 0, 0, 0);
        f32x4 h2bv = __builtin_amdgcn_mfma_f32_16x16x32_f16(A2h[1], B2bv, ZF, 0, 0, 0);

        // ---- z dot products (u, v interleaved) ----
        float zpau = fmaxf(h2au[0], 0.f) * w3v[0][0];
        float zpav = fmaxf(h2av[0], 0.f) * w3v[0][0];
        zpau = fmaf(fmaxf(h2au[1], 0.f), w3v[0][1], zpau);
        zpav = fmaf(fmaxf(h2av[1], 0.f), w3v[0][1], zpav);
        zpau = fmaf(fmaxf(h2au[2], 0.f), w3v[0][2], zpau);
        zpav = fmaf(fmaxf(h2av[2], 0.f), w3v[0][2], zpav);
        zpau = fmaf(fmaxf(h2au[3], 0.f), w3v[0][3], zpau);
        zpav = fmaf(fmaxf(h2av[3], 0.f), w3v[0][3], zpav);
        float zpbu = fmaxf(h2bu[0], 0.f) * w3v[1][0];
        float zpbv = fmaxf(h2bv[0], 0.f) * w3v[1][0];
        zpbu = fmaf(fmaxf(h2bu[1], 0.f), w3v[1][1], zpbu);
        zpbv = fmaf(fmaxf(h2bv[1], 0.f), w3v[1][1], zpbv);
        zpbu = fmaf(fmaxf(h2bu[2], 0.f), w3v[1][2], zpbu);
        zpbv = fmaf(fmaxf(h2bv[2], 0.f), w3v[1][2], zpbv);
        zpbu = fmaf(fmaxf(h2bu[3], 0.f), w3v[1][3], zpbu);
        zpbv = fmaf(fmaxf(h2bv[3], 0.f), w3v[1][3], zpbv);

        // ---- cross-half reduce: 4 shfls, two independent pairs ----
        zpau += __shfl_xor(zpau, 16);
        zpav += __shfl_xor(zpav, 16);
        zpbu += __shfl_xor(zpbu, 16);
        zpbv += __shfl_xor(zpbv, 16);

        // ---- sigmoid + dice (u, v) ----
        const float zu = (par ? zpbu : zpau) + b3S;
        const float zv = (par ? zpbv : zpav) + b3S;
        const float ou = __builtin_amdgcn_rcpf(1.f + __expf(-zu));
        const float ov = __builtin_amdgcn_rcpf(1.f + __expf(-zv));
        const float fou = flS * ou;
        const float fov = flS * ov;
        inter = fmaf(fou, tvu, inter);
        inter = fmaf(fov, tvv, inter);
        ps    = fmaf(fou, ou, ps);
        ps    = fmaf(fov, ov, ps);
        ts    = fmaf(flS, tvu * tvu, ts);
        ts    = fmaf(flS, tvv * tvv, ts);
    }

    // wave reduce then cross-wave
    #pragma unroll
    for (int off = 32; off > 0; off >>= 1) {
        inter += __shfl_down(inter, off);
        ps    += __shfl_down(ps,    off);
        ts    += __shfl_down(ts,    off);
    }
    __shared__ float red[3][4];
    if ((tid & 63) == 0) { red[0][wave] = inter; red[1][wave] = ps; red[2][wave] = ts; }
    __syncthreads();
    if (tid == 0) {
        red_base[(b * 3 + 0) * SLOTS + rest] = red[0][0] + red[0][1] + red[0][2] + red[0][3];
        red_base[(b * 3 + 1) * SLOTS + rest] = red[1][0] + red[1][1] + red[1][2] + red[1][3];
        red_base[(b * 3 + 2) * SLOTS + rest] = red[2][0] + red[2][1] + red[2][2] + red[2][3];
    }
}

// deterministic epilogue: 24 series x 256 partials
__global__ void seg_dice_final(const float* __restrict__ red_base, float* __restrict__ out) {
    __shared__ float red[24][4];
    const int tid = threadIdx.x;  // 128 threads
    if (tid < 96) {
        const int series = tid >> 2;
        const int part   = tid & 3;
        const float4* p = (const float4*)(red_base + series * SLOTS + part * 64);
        float s = 0.f;
        #pragma unroll
        for (int i = 0; i < 16; ++i) { const float4 v = p[i]; s += (v.x + v.y) + (v.z + v.w); }
        red[series][part] = s;
    }
    __syncthreads();
    if (tid == 0) {
        float acc = 0.f;
        #pragma unroll
        for (int b = 0; b < Bb; ++b) {
            const float inter = red[b*3+0][0] + red[b*3+0][1] + red[b*3+0][2] + red[b*3+0][3];
            const float p2    = red[b*3+1][0] + red[b*3+1][1] + red[b*3+1][2] + red[b*3+1][3];
            const float t2    = red[b*3+2][0] + red[b*3+2][1] + red[b*3+2][2] + red[b*3+2][3];
            acc += 1.0f - (2.0f * inter + 1.0f) / (p2 + t2 + 1.0f);
        }
        out[0] = acc * (1.0f / (float)Bb);
    }
}

extern "C" void kernel_launch(void* const* d_in, const int* in_sizes, int n_in,
                              void* d_out, int out_size, void* d_ws, size_t ws_size,
                              hipStream_t stream) {
    const float* seg_feat    = (const float*)d_in[0];
    const float* conv_weight = (const float*)d_in[1];
    const float* mask        = (const float*)d_in[2];
    const int*   ind         = (const int*)d_in[3];
    const float* target      = (const float*)d_in[4];
    float* out = (float*)d_out;

    uint32_t* fragtab  = (uint32_t*)d_ws;
    float*    red_base = (float*)d_ws + FRAG_U32;

    pack_frags<<<256, 64, 0, stream>>>(conv_weight, mask, ind, fragtab);
    seg_dice_main<<<NBLK, 256, 0, stream>>>(seg_feat, target, fragtab, red_base);
    seg_dice_final<<<1, 128, 0, stream>>>(red_base, out);
}